// Round 3
// baseline (721.269 us; speedup 1.0000x reference)
//
#include <hip/hip_runtime.h>
#include <math.h>

#define E 16
#define D 64
#define H 128
#define R 4            // n-rows per block == waves per block

// ---------------------------------------------------------------------------
// Prep: Wabc[c][j] = Wa + Wb + Wc  (spec_W1 rows 0..127, 128..255, 256..383)
// ---------------------------------------------------------------------------
__global__ void wabc_prep(const float* __restrict__ specW1, float* __restrict__ wabc) {
    int i = blockIdx.x * blockDim.x + threadIdx.x;
    if (i < H * H) {
        wabc[i] = specW1[i] + specW1[H * H + i] + specW1[2 * H * H + i];
    }
}

// ---------------------------------------------------------------------------
// Fused router, zero-__syncthreads design.
// Block = 256 threads (4 waves). Wave wq owns n-row (blockIdx.x*R + wq) and a
// private 8 KB LDS slice (buf + wq*2048 floats) + private stats rows. All
// cross-lane exchange is intra-wave (lockstep + in-order LDS), so no barriers
// are needed anywhere. LDS = 38,912 B -> 4 blocks/CU = 16 waves/CU.
// __launch_bounds__(256,2): (256,4) made hipcc cap VGPRs at 64 and spill
// ~4 KB/wave to scratch (measured: WRITE_SIZE 81 MB). With (256,2) the
// compiler allocates ~96 VGPRs (round-0 evidence), still <=128 so the HW can
// run 4 waves/SIMD; occupancy stays LDS-capped at 4 blocks/CU.
// buf slice lifecycle: tokens[16][64] -> h[16][128] -> encoded[16][128]
//                      -> (first 16 floats) logits.
// Bias GEMV: lane=(kh,j4), K split across half-waves, __shfl_xor(32) combine;
// bias kept in registers (same j4 layout as spec-GEMM epilogue needs).
// ---------------------------------------------------------------------------
template <bool USE_WABC>
__global__ __launch_bounds__(256, 2)
void router_kernel(const float* __restrict__ tokens,
                   const float* __restrict__ encW1, const float* __restrict__ encB1,
                   const float* __restrict__ encW2, const float* __restrict__ encB2,
                   const float* __restrict__ specW1, const float* __restrict__ specB1,
                   const float* __restrict__ specW2,
                   const float* __restrict__ defW1, const float* __restrict__ defB1,
                   const float* __restrict__ defW2, const float* __restrict__ defB2,
                   const int* __restrict__ fiPtr, const int* __restrict__ tkPtr,
                   const float* __restrict__ wabc,
                   float* __restrict__ out, int N) {
    __shared__ float buf[R * E * H];   // 32 KB, wave-partitioned
    __shared__ float s_full[R * H];    // 2 KB
    __shared__ float s_glob[R * H];    // 2 KB
    __shared__ float s_mabs[R * H];    // 2 KB

    const int tid  = threadIdx.x;
    const int lane = tid & 63;
    const int wq   = tid >> 6;
    const int n    = blockIdx.x * R + wq;
    if (n >= N) return;               // wave-uniform; legal (no barriers below)

    const int fi  = fiPtr[0];
    const int hw  = lane >> 5;         // half-wave: rows 0..7 / 8..15 (or K-half)
    const int jl  = lane & 31;
    const int jw0 = jl * 4;            // this lane's 4-col chunk
    float* __restrict__ wbuf = buf + wq * (E * H);

    // ---- stage 1: coalesced token load: 16 expert-rows x 64 = 4 KB ----
    {
        const float4* __restrict__ src = (const float4*)(tokens + (size_t)n * (E * D));
        float4* dst = (float4*)wbuf;
#pragma unroll
        for (int it = 0; it < 4; it++) dst[lane + it * 64] = src[lane + it * 64];
    }
    __builtin_amdgcn_wave_barrier();

    // ---- stage 2: enc1  h = relu(tok @ W1 + b1), K=64; tokens -> h in place ----
    {
        float acc[8][4];
#pragma unroll
        for (int m = 0; m < 8; m++)
#pragma unroll
            for (int j = 0; j < 4; j++) acc[m][j] = 0.f;
#pragma unroll 2
        for (int k = 0; k < D; k += 4) {
            float4 w0 = *(const float4*)(encW1 + (k + 0) * H + jw0);
            float4 w1 = *(const float4*)(encW1 + (k + 1) * H + jw0);
            float4 w2 = *(const float4*)(encW1 + (k + 2) * H + jw0);
            float4 w3 = *(const float4*)(encW1 + (k + 3) * H + jw0);
#pragma unroll
            for (int m = 0; m < 8; m++) {
                float4 t = *(const float4*)(wbuf + (hw * 8 + m) * D + k);
                acc[m][0] = fmaf(t.w, w3.x, fmaf(t.z, w2.x, fmaf(t.y, w1.x, fmaf(t.x, w0.x, acc[m][0]))));
                acc[m][1] = fmaf(t.w, w3.y, fmaf(t.z, w2.y, fmaf(t.y, w1.y, fmaf(t.x, w0.y, acc[m][1]))));
                acc[m][2] = fmaf(t.w, w3.z, fmaf(t.z, w2.z, fmaf(t.y, w1.z, fmaf(t.x, w0.z, acc[m][2]))));
                acc[m][3] = fmaf(t.w, w3.w, fmaf(t.z, w2.w, fmaf(t.y, w1.w, fmaf(t.x, w0.w, acc[m][3]))));
            }
        }
        float4 b = *(const float4*)(encB1 + jw0);
        __builtin_amdgcn_wave_barrier();   // all token reads precede h writes
#pragma unroll
        for (int m = 0; m < 8; m++) {
            float4 o;
            o.x = fmaxf(acc[m][0] + b.x, 0.f);
            o.y = fmaxf(acc[m][1] + b.y, 0.f);
            o.z = fmaxf(acc[m][2] + b.z, 0.f);
            o.w = fmaxf(acc[m][3] + b.w, 0.f);
            *(float4*)(wbuf + (hw * 8 + m) * H + jw0) = o;
        }
    }
    __builtin_amdgcn_wave_barrier();

    // ---- stage 3: enc2  encoded = relu(h @ W2 + b2), K=128; h -> enc in place ----
    {
        float acc[8][4];
#pragma unroll
        for (int m = 0; m < 8; m++)
#pragma unroll
            for (int j = 0; j < 4; j++) acc[m][j] = 0.f;
#pragma unroll 2
        for (int k = 0; k < H; k += 4) {
            float4 w0 = *(const float4*)(encW2 + (k + 0) * H + jw0);
            float4 w1 = *(const float4*)(encW2 + (k + 1) * H + jw0);
            float4 w2 = *(const float4*)(encW2 + (k + 2) * H + jw0);
            float4 w3 = *(const float4*)(encW2 + (k + 3) * H + jw0);
#pragma unroll
            for (int m = 0; m < 8; m++) {
                float4 t = *(const float4*)(wbuf + (hw * 8 + m) * H + k);
                acc[m][0] = fmaf(t.w, w3.x, fmaf(t.z, w2.x, fmaf(t.y, w1.x, fmaf(t.x, w0.x, acc[m][0]))));
                acc[m][1] = fmaf(t.w, w3.y, fmaf(t.z, w2.y, fmaf(t.y, w1.y, fmaf(t.x, w0.y, acc[m][1]))));
                acc[m][2] = fmaf(t.w, w3.z, fmaf(t.z, w2.z, fmaf(t.y, w1.z, fmaf(t.x, w0.z, acc[m][2]))));
                acc[m][3] = fmaf(t.w, w3.w, fmaf(t.z, w2.w, fmaf(t.y, w1.w, fmaf(t.x, w0.w, acc[m][3]))));
            }
        }
        float4 b = *(const float4*)(encB2 + jw0);
        __builtin_amdgcn_wave_barrier();   // all h reads precede encoded writes
#pragma unroll
        for (int m = 0; m < 8; m++) {
            float4 o;
            o.x = fmaxf(acc[m][0] + b.x, 0.f);
            o.y = fmaxf(acc[m][1] + b.y, 0.f);
            o.z = fmaxf(acc[m][2] + b.z, 0.f);
            o.w = fmaxf(acc[m][3] + b.w, 0.f);
            *(float4*)(wbuf + (hw * 8 + m) * H + jw0) = o;
        }
    }
    __builtin_amdgcn_wave_barrier();

    // ---- stage 4: stats (full, glob mean, mean|delta|), 2 cols/lane ----
    {
        const int c2 = lane * 2;
        float2 fc = *(const float2*)(wbuf + fi * H + c2);
        float sx = 0.f, sy = 0.f, mx = 0.f, my = 0.f;
#pragma unroll
        for (int e = 0; e < E; e++) {
            float2 v = *(const float2*)(wbuf + e * H + c2);
            sx += v.x; sy += v.y;
            mx += fabsf(v.x - fc.x); my += fabsf(v.y - fc.y);
        }
        *(float2*)(s_full + wq * H + c2) = fc;
        *(float2*)(s_glob + wq * H + c2) = make_float2(sx * 0.0625f, sy * 0.0625f);
        *(float2*)(s_mabs + wq * H + c2) = make_float2(mx * 0.0625f, my * 0.0625f);
    }
    __builtin_amdgcn_wave_barrier();

    // ---- stage 5: per-wave bias/defer GEMV; lane=(K-half hw, cols jw0..+3) ----
    float4 biasr;
    {
        const float* __restrict__ Wb = specW1 + H * H;
        const float* __restrict__ Wc = specW1 + 2 * H * H;
        const int c0 = hw * 64;
        float accB[4] = {0.f, 0.f, 0.f, 0.f};
        float accD[4] = {0.f, 0.f, 0.f, 0.f};
#pragma unroll 2
        for (int cc = 0; cc < 64; cc++) {
            const int c = c0 + cc;
            float4 wb = *(const float4*)(Wb + c * H + jw0);
            float4 wc = *(const float4*)(Wc + c * H + jw0);
            float4 d0 = *(const float4*)(defW1 + c * H + jw0);
            float4 d1 = *(const float4*)(defW1 + (H + c) * H + jw0);
            float4 d2 = *(const float4*)(defW1 + (2 * H + c) * H + jw0);
            float fv = s_full[wq * H + c];
            float gv = s_glob[wq * H + c];
            float mv = s_mabs[wq * H + c];
            accB[0] = fmaf(gv, wc.x, fmaf(fv, wb.x, accB[0]));
            accB[1] = fmaf(gv, wc.y, fmaf(fv, wb.y, accB[1]));
            accB[2] = fmaf(gv, wc.z, fmaf(fv, wb.z, accB[2]));
            accB[3] = fmaf(gv, wc.w, fmaf(fv, wb.w, accB[3]));
            accD[0] = fmaf(mv, d2.x, fmaf(gv, d1.x, fmaf(fv, d0.x, accD[0])));
            accD[1] = fmaf(mv, d2.y, fmaf(gv, d1.y, fmaf(fv, d0.y, accD[1])));
            accD[2] = fmaf(mv, d2.z, fmaf(gv, d1.z, fmaf(fv, d0.z, accD[2])));
            accD[3] = fmaf(mv, d2.w, fmaf(gv, d1.w, fmaf(fv, d0.w, accD[3])));
        }
#pragma unroll
        for (int t = 0; t < 4; t++) {
            accB[t] += __shfl_xor(accB[t], 32, 64);
            accD[t] += __shfl_xor(accD[t], 32, 64);
        }
        float4 sb = *(const float4*)(specB1 + jw0);
        biasr = make_float4(sb.x - accB[0], sb.y - accB[1], sb.z - accB[2], sb.w - accB[3]);
        float4 db = *(const float4*)(defB1 + jw0);
        float4 dw = *(const float4*)(defW2 + jw0);
        float dv = fmaxf(db.x + accD[0], 0.f) * dw.x
                 + fmaxf(db.y + accD[1], 0.f) * dw.y
                 + fmaxf(db.z + accD[2], 0.f) * dw.z
                 + fmaxf(db.w + accD[3], 0.f) * dw.w;
#pragma unroll
        for (int off = 1; off < 32; off <<= 1) dv += __shfl_xor(dv, off, 64);
        if (lane == 0) {
            float s = dv + defB2[0];
            out[(size_t)N * E + n] = 1.f / (1.f + expf(-s));
        }
    }

    // ---- stage 6: spec GEMM: relu(enc@Wabc + |enc-full|@Wd + bias) -> logits ----
    {
        float acc[8][4];
#pragma unroll
        for (int m = 0; m < 8; m++)
#pragma unroll
            for (int j = 0; j < 4; j++) acc[m][j] = 0.f;
        const float* __restrict__ Wd = specW1 + 3 * H * H;
        for (int k = 0; k < H; k += 4) {
            float4 wa0, wa1, wa2, wa3;
            if (USE_WABC) {
                wa0 = *(const float4*)(wabc + (k + 0) * H + jw0);
                wa1 = *(const float4*)(wabc + (k + 1) * H + jw0);
                wa2 = *(const float4*)(wabc + (k + 2) * H + jw0);
                wa3 = *(const float4*)(wabc + (k + 3) * H + jw0);
            } else {
#pragma unroll
                for (int t = 0; t < 4; t++) {
                    const float* p = specW1 + (k + t) * H + jw0;
                    float4 x0 = *(const float4*)(p);
                    float4 x1 = *(const float4*)(p + H * H);
                    float4 x2 = *(const float4*)(p + 2 * H * H);
                    float4 s4 = make_float4(x0.x + x1.x + x2.x, x0.y + x1.y + x2.y,
                                            x0.z + x1.z + x2.z, x0.w + x1.w + x2.w);
                    if (t == 0) wa0 = s4; else if (t == 1) wa1 = s4;
                    else if (t == 2) wa2 = s4; else wa3 = s4;
                }
            }
            float4 wd0 = *(const float4*)(Wd + (k + 0) * H + jw0);
            float4 wd1 = *(const float4*)(Wd + (k + 1) * H + jw0);
            float4 wd2 = *(const float4*)(Wd + (k + 2) * H + jw0);
            float4 wd3 = *(const float4*)(Wd + (k + 3) * H + jw0);
            float4 f4 = *(const float4*)(s_full + wq * H + k);   // uniform broadcast
#pragma unroll
            for (int m = 0; m < 8; m++) {
                float4 ev = *(const float4*)(wbuf + (hw * 8 + m) * H + k);
                float ax = fabsf(ev.x - f4.x);
                float ay = fabsf(ev.y - f4.y);
                float az = fabsf(ev.z - f4.z);
                float aw = fabsf(ev.w - f4.w);
#pragma unroll
                for (int j = 0; j < 4; j++) {
                    const float* waj0 = &wa0.x, *waj1 = &wa1.x, *waj2 = &wa2.x, *waj3 = &wa3.x;
                    const float* wdj0 = &wd0.x, *wdj1 = &wd1.x, *wdj2 = &wd2.x, *wdj3 = &wd3.x;
                    float a = acc[m][j];
                    a = fmaf(ev.x, waj0[j], a);
                    a = fmaf(ev.y, waj1[j], a);
                    a = fmaf(ev.z, waj2[j], a);
                    a = fmaf(ev.w, waj3[j], a);
                    a = fmaf(ax, wdj0[j], a);
                    a = fmaf(ay, wdj1[j], a);
                    a = fmaf(az, wdj2[j], a);
                    a = fmaf(aw, wdj3[j], a);
                    acc[m][j] = a;
                }
            }
        }
        // epilogue: logit per row via 32-lane reduce; store into own buf slice
        float4 w2 = *(const float4*)(specW2 + jw0);
        __builtin_amdgcn_wave_barrier();   // all encoded reads precede logit writes
#pragma unroll
        for (int m = 0; m < 8; m++) {
            float p = 0.f;
            p += fmaxf(acc[m][0] + biasr.x, 0.f) * w2.x;
            p += fmaxf(acc[m][1] + biasr.y, 0.f) * w2.y;
            p += fmaxf(acc[m][2] + biasr.z, 0.f) * w2.z;
            p += fmaxf(acc[m][3] + biasr.w, 0.f) * w2.w;
#pragma unroll
            for (int off = 1; off < 32; off <<= 1) p += __shfl_xor(p, off, 64);
            if (jl == 0) wbuf[hw * 8 + m] = p;   // logit for expert e = hw*8+m
        }
    }
    __builtin_amdgcn_wave_barrier();

    // ---- stage 7: finalize this wave's n-row (lane 0): top-k + softmax ----
    if (lane == 0) {
        int k = tkPtr[0];
        if (k < 1) k = 1;
        if (k > E - 1) k = E - 1;
        unsigned chosen = 0u;
        for (int kk = 0; kk < k; kk++) {
            float bv = -INFINITY;
            int bi = 0;
            for (int e = 0; e < E; e++) {
                if (e == fi || ((chosen >> e) & 1u)) continue;
                float v = wbuf[e];
                if (v > bv) { bv = v; bi = e; }
            }
            chosen |= (1u << bi);
        }
        float mx = -INFINITY;
        for (int e = 0; e < E; e++)
            if ((chosen >> e) & 1u) { float v = wbuf[e]; if (v > mx) mx = v; }
        float ssum = 0.f;
        for (int e = 0; e < E; e++)
            if ((chosen >> e) & 1u) ssum += expf(wbuf[e] - mx);
        float inv = 1.f / ssum;
        for (int e = 0; e < E; e++) {
            float wv = 0.f;
            if ((chosen >> e) & 1u) wv = expf(wbuf[e] - mx) * inv;
            out[(size_t)n * E + e] = wv;
        }
    }
}

extern "C" void kernel_launch(void* const* d_in, const int* in_sizes, int n_in,
                              void* d_out, int out_size, void* d_ws, size_t ws_size,
                              hipStream_t stream) {
    (void)n_in; (void)out_size;
    const float* tokens = (const float*)d_in[0];
    const float* encW1  = (const float*)d_in[1];
    const float* encB1  = (const float*)d_in[2];
    const float* encW2  = (const float*)d_in[3];
    const float* encB2  = (const float*)d_in[4];
    const float* specW1 = (const float*)d_in[5];
    const float* specB1 = (const float*)d_in[6];
    const float* specW2 = (const float*)d_in[7];
    // d_in[8] = spec_b2 (unused: softmax is shift-invariant)
    const float* defW1  = (const float*)d_in[9];
    const float* defB1  = (const float*)d_in[10];
    const float* defW2  = (const float*)d_in[11];
    const float* defB2  = (const float*)d_in[12];
    const int*   fiPtr  = (const int*)d_in[13];
    const int*   tkPtr  = (const int*)d_in[14];
    float* out = (float*)d_out;

    const int N = in_sizes[0] / (E * D);
    const int grid = (N + R - 1) / R;
    const bool useWs = (d_ws != nullptr) && (ws_size >= (size_t)(H * H * sizeof(float)));

    if (useWs) {
        wabc_prep<<<(H * H + 255) / 256, 256, 0, stream>>>(specW1, (float*)d_ws);
        router_kernel<true><<<grid, 256, 0, stream>>>(
            tokens, encW1, encB1, encW2, encB2, specW1, specB1, specW2,
            defW1, defB1, defW2, defB2, fiPtr, tkPtr, (const float*)d_ws, out, N);
    } else {
        router_kernel<false><<<grid, 256, 0, stream>>>(
            tokens, encW1, encB1, encW2, encB2, specW1, specB1, specW2,
            defW1, defB1, defW2, defB2, fiPtr, tkPtr, nullptr, out, N);
    }
}

// Round 4
// 698.710 us; speedup vs baseline: 1.0323x; 1.0323x over previous
//
#include <hip/hip_runtime.h>
#include <math.h>

#define E 16
#define D 64
#define H 128
#define R 4            // n-rows per block == waves per block

// ---------------------------------------------------------------------------
// Prep: Wabc[c][j] = Wa + Wb + Wc  (spec_W1 rows 0..127, 128..255, 256..383)
// ---------------------------------------------------------------------------
__global__ void wabc_prep(const float* __restrict__ specW1, float* __restrict__ wabc) {
    int i = blockIdx.x * blockDim.x + threadIdx.x;
    if (i < H * H) {
        wabc[i] = specW1[i] + specW1[H * H + i] + specW1[2 * H * H + i];
    }
}

// ---------------------------------------------------------------------------
// Fused router. Block = 256 threads (4 waves). Wave wq owns n-row
// (blockIdx.x*R + wq) and a private 8 KB LDS slice. Stages 1-4, 6, 7 are
// wave-private (wave_barrier only). Stage 5 (bias/defer GEMV) is the one
// block-cooperative phase: it streams 5 HxH weight matrices (320 KB) with
// zero reuse, so the 4 waves split the K dimension 4 ways (wave wq reads
// only c in [wq*32, wq*32+32) of ALL 5 matrices) and each computes partials
// for ALL 4 n-rows. Per-wave GEMV traffic drops 320 KB -> 80 KB (4x); total
// GEMV FMA unchanged. Partials exchanged via an 8 KB slab reused for the
// B-phase (bias) then D-phase (defer), costing 4 __syncthreads.
// LDS = 47,104 B -> 3 blocks/CU.
// __launch_bounds__(256,2): (256,4) capped VGPRs at 64 and spilled 4 KB/wave
// (r1: WRITE_SIZE 81 MB). 92 VGPR under (256,2) -> 4 waves/SIMD possible.
// ---------------------------------------------------------------------------
template <bool USE_WABC>
__global__ __launch_bounds__(256, 2)
void router_kernel(const float* __restrict__ tokens,
                   const float* __restrict__ encW1, const float* __restrict__ encB1,
                   const float* __restrict__ encW2, const float* __restrict__ encB2,
                   const float* __restrict__ specW1, const float* __restrict__ specB1,
                   const float* __restrict__ specW2,
                   const float* __restrict__ defW1, const float* __restrict__ defB1,
                   const float* __restrict__ defW2, const float* __restrict__ defB2,
                   const int* __restrict__ fiPtr, const int* __restrict__ tkPtr,
                   const float* __restrict__ wabc,
                   float* __restrict__ out, int N) {
    __shared__ float buf[R * E * H];     // 32 KB, wave-partitioned
    __shared__ float s_full[R * H];      // 2 KB
    __shared__ float s_glob[R * H];      // 2 KB
    __shared__ float s_mabs[R * H];      // 2 KB
    __shared__ float s_part[R * R * H];  // 8 KB: GEMV partials [wave][row][H]

    const int tid  = threadIdx.x;
    const int lane = tid & 63;
    const int wq   = tid >> 6;
    const int n    = blockIdx.x * R + wq;
    const bool active = (n < N);       // wave-uniform; all waves reach barriers

    const int fi  = fiPtr[0];
    const int hw  = lane >> 5;         // half-wave: rows 0..7 / 8..15 (or K-half)
    const int jl  = lane & 31;
    const int jw0 = jl * 4;            // this lane's 4-col chunk
    float* __restrict__ wbuf = buf + wq * (E * H);

    if (active) {
        // ---- stage 1: coalesced token load: 16 expert-rows x 64 = 4 KB ----
        {
            const float4* __restrict__ src = (const float4*)(tokens + (size_t)n * (E * D));
            float4* dst = (float4*)wbuf;
#pragma unroll
            for (int it = 0; it < 4; it++) dst[lane + it * 64] = src[lane + it * 64];
        }
        __builtin_amdgcn_wave_barrier();

        // ---- stage 2: enc1  h = relu(tok @ W1 + b1), K=64; in place ----
        {
            float acc[8][4];
#pragma unroll
            for (int m = 0; m < 8; m++)
#pragma unroll
                for (int j = 0; j < 4; j++) acc[m][j] = 0.f;
#pragma unroll 2
            for (int k = 0; k < D; k += 4) {
                float4 w0 = *(const float4*)(encW1 + (k + 0) * H + jw0);
                float4 w1 = *(const float4*)(encW1 + (k + 1) * H + jw0);
                float4 w2 = *(const float4*)(encW1 + (k + 2) * H + jw0);
                float4 w3 = *(const float4*)(encW1 + (k + 3) * H + jw0);
#pragma unroll
                for (int m = 0; m < 8; m++) {
                    float4 t = *(const float4*)(wbuf + (hw * 8 + m) * D + k);
                    acc[m][0] = fmaf(t.w, w3.x, fmaf(t.z, w2.x, fmaf(t.y, w1.x, fmaf(t.x, w0.x, acc[m][0]))));
                    acc[m][1] = fmaf(t.w, w3.y, fmaf(t.z, w2.y, fmaf(t.y, w1.y, fmaf(t.x, w0.y, acc[m][1]))));
                    acc[m][2] = fmaf(t.w, w3.z, fmaf(t.z, w2.z, fmaf(t.y, w1.z, fmaf(t.x, w0.z, acc[m][2]))));
                    acc[m][3] = fmaf(t.w, w3.w, fmaf(t.z, w2.w, fmaf(t.y, w1.w, fmaf(t.x, w0.w, acc[m][3]))));
                }
            }
            float4 b = *(const float4*)(encB1 + jw0);
            __builtin_amdgcn_wave_barrier();   // all token reads precede h writes
#pragma unroll
            for (int m = 0; m < 8; m++) {
                float4 o;
                o.x = fmaxf(acc[m][0] + b.x, 0.f);
                o.y = fmaxf(acc[m][1] + b.y, 0.f);
                o.z = fmaxf(acc[m][2] + b.z, 0.f);
                o.w = fmaxf(acc[m][3] + b.w, 0.f);
                *(float4*)(wbuf + (hw * 8 + m) * H + jw0) = o;
            }
        }
        __builtin_amdgcn_wave_barrier();

        // ---- stage 3: enc2  encoded = relu(h @ W2 + b2), K=128; in place ----
        {
            float acc[8][4];
#pragma unroll
            for (int m = 0; m < 8; m++)
#pragma unroll
                for (int j = 0; j < 4; j++) acc[m][j] = 0.f;
#pragma unroll 2
            for (int k = 0; k < H; k += 4) {
                float4 w0 = *(const float4*)(encW2 + (k + 0) * H + jw0);
                float4 w1 = *(const float4*)(encW2 + (k + 1) * H + jw0);
                float4 w2 = *(const float4*)(encW2 + (k + 2) * H + jw0);
                float4 w3 = *(const float4*)(encW2 + (k + 3) * H + jw0);
#pragma unroll
                for (int m = 0; m < 8; m++) {
                    float4 t = *(const float4*)(wbuf + (hw * 8 + m) * H + k);
                    acc[m][0] = fmaf(t.w, w3.x, fmaf(t.z, w2.x, fmaf(t.y, w1.x, fmaf(t.x, w0.x, acc[m][0]))));
                    acc[m][1] = fmaf(t.w, w3.y, fmaf(t.z, w2.y, fmaf(t.y, w1.y, fmaf(t.x, w0.y, acc[m][1]))));
                    acc[m][2] = fmaf(t.w, w3.z, fmaf(t.z, w2.z, fmaf(t.y, w1.z, fmaf(t.x, w0.z, acc[m][2]))));
                    acc[m][3] = fmaf(t.w, w3.w, fmaf(t.z, w2.w, fmaf(t.y, w1.w, fmaf(t.x, w0.w, acc[m][3]))));
                }
            }
            float4 b = *(const float4*)(encB2 + jw0);
            __builtin_amdgcn_wave_barrier();   // all h reads precede encoded writes
#pragma unroll
            for (int m = 0; m < 8; m++) {
                float4 o;
                o.x = fmaxf(acc[m][0] + b.x, 0.f);
                o.y = fmaxf(acc[m][1] + b.y, 0.f);
                o.z = fmaxf(acc[m][2] + b.z, 0.f);
                o.w = fmaxf(acc[m][3] + b.w, 0.f);
                *(float4*)(wbuf + (hw * 8 + m) * H + jw0) = o;
            }
        }
        __builtin_amdgcn_wave_barrier();

        // ---- stage 4: stats (full, glob mean, mean|delta|), 2 cols/lane ----
        {
            const int c2 = lane * 2;
            float2 fc = *(const float2*)(wbuf + fi * H + c2);
            float sx = 0.f, sy = 0.f, mx = 0.f, my = 0.f;
#pragma unroll
            for (int e = 0; e < E; e++) {
                float2 v = *(const float2*)(wbuf + e * H + c2);
                sx += v.x; sy += v.y;
                mx += fabsf(v.x - fc.x); my += fabsf(v.y - fc.y);
            }
            *(float2*)(s_full + wq * H + c2) = fc;
            *(float2*)(s_glob + wq * H + c2) = make_float2(sx * 0.0625f, sy * 0.0625f);
            *(float2*)(s_mabs + wq * H + c2) = make_float2(mx * 0.0625f, my * 0.0625f);
        }
    }
    __syncthreads();   // #1: all rows' stats visible to all waves

    // ---- stage 5a: cooperative GEMV partials. Wave wq covers c-quarter
    //      [wq*32, wq*32+32) of Wb, Wc, defW1[0..2] for ALL R rows. Lane
    //      (hw, jl): hw halves the quarter (16 c each), jl*4 = j-cols.
    //      Inactive waves still run this (active rows need their c-quarter);
    //      garbage stats of inactive ROWS only poison those rows' partials. ----
    float accB[R][4];
    float accD[R][4];
    {
        const float* __restrict__ Wb = specW1 + H * H;
        const float* __restrict__ Wc = specW1 + 2 * H * H;
        const int cbase = wq * 32 + hw * 16;
#pragma unroll
        for (int r = 0; r < R; r++)
#pragma unroll
            for (int j = 0; j < 4; j++) { accB[r][j] = 0.f; accD[r][j] = 0.f; }
        for (int c4 = 0; c4 < 4; c4++) {           // 4 chunks of 4 c
            float4 fv4[R], gv4[R], mv4[R];
#pragma unroll
            for (int r = 0; r < R; r++) {
                fv4[r] = *(const float4*)(s_full + r * H + cbase + c4 * 4);
                gv4[r] = *(const float4*)(s_glob + r * H + cbase + c4 * 4);
                mv4[r] = *(const float4*)(s_mabs + r * H + cbase + c4 * 4);
            }
#pragma unroll
            for (int cc = 0; cc < 4; cc++) {
                const int c = cbase + c4 * 4 + cc;
                float4 wb = *(const float4*)(Wb + c * H + jw0);
                float4 wc = *(const float4*)(Wc + c * H + jw0);
                float4 d0 = *(const float4*)(defW1 + c * H + jw0);
                float4 d1 = *(const float4*)(defW1 + (H + c) * H + jw0);
                float4 d2 = *(const float4*)(defW1 + (2 * H + c) * H + jw0);
#pragma unroll
                for (int r = 0; r < R; r++) {
                    const float fv = (&fv4[r].x)[cc];
                    const float gv = (&gv4[r].x)[cc];
                    const float mv = (&mv4[r].x)[cc];
                    accB[r][0] = fmaf(gv, wc.x, fmaf(fv, wb.x, accB[r][0]));
                    accB[r][1] = fmaf(gv, wc.y, fmaf(fv, wb.y, accB[r][1]));
                    accB[r][2] = fmaf(gv, wc.z, fmaf(fv, wb.z, accB[r][2]));
                    accB[r][3] = fmaf(gv, wc.w, fmaf(fv, wb.w, accB[r][3]));
                    accD[r][0] = fmaf(mv, d2.x, fmaf(gv, d1.x, fmaf(fv, d0.x, accD[r][0])));
                    accD[r][1] = fmaf(mv, d2.y, fmaf(gv, d1.y, fmaf(fv, d0.y, accD[r][1])));
                    accD[r][2] = fmaf(mv, d2.z, fmaf(gv, d1.z, fmaf(fv, d0.z, accD[r][2])));
                    accD[r][3] = fmaf(mv, d2.w, fmaf(gv, d1.w, fmaf(fv, d0.w, accD[r][3])));
                }
            }
        }
        // combine half-wave (hw) K-halves of this quarter
#pragma unroll
        for (int r = 0; r < R; r++)
#pragma unroll
            for (int j = 0; j < 4; j++) {
                accB[r][j] += __shfl_xor(accB[r][j], 32, 64);
                accD[r][j] += __shfl_xor(accD[r][j], 32, 64);
            }
        // store B-partials (hw splits rows: no duplicate writes)
#pragma unroll
        for (int rr = 0; rr < 2; rr++) {
            const int r = hw * 2 + rr;
            *(float4*)(s_part + (wq * R + r) * H + jw0) =
                make_float4(accB[r][0], accB[r][1], accB[r][2], accB[r][3]);
        }
    }
    __syncthreads();   // #2: B-partials ready

    // ---- stage 5b: combine B-partials -> biasr (registers) ----
    float4 biasr;
    {
        float4 p0 = *(const float4*)(s_part + (0 * R + wq) * H + jw0);
        float4 p1 = *(const float4*)(s_part + (1 * R + wq) * H + jw0);
        float4 p2 = *(const float4*)(s_part + (2 * R + wq) * H + jw0);
        float4 p3 = *(const float4*)(s_part + (3 * R + wq) * H + jw0);
        float4 sb = *(const float4*)(specB1 + jw0);
        biasr.x = sb.x - (((p0.x + p1.x) + p2.x) + p3.x);
        biasr.y = sb.y - (((p0.y + p1.y) + p2.y) + p3.y);
        biasr.z = sb.z - (((p0.z + p1.z) + p2.z) + p3.z);
        biasr.w = sb.w - (((p0.w + p1.w) + p2.w) + p3.w);
    }
    __syncthreads();   // #3: all B-reads done before slab reuse

    // ---- stage 5c: store D-partials into reused slab ----
    {
#pragma unroll
        for (int rr = 0; rr < 2; rr++) {
            const int r = hw * 2 + rr;
            *(float4*)(s_part + (wq * R + r) * H + jw0) =
                make_float4(accD[r][0], accD[r][1], accD[r][2], accD[r][3]);
        }
    }
    __syncthreads();   // #4: D-partials ready

    if (!active) return;

    // ---- stage 5d: defer head: combine D-partials, relu, dot w/ defW2 ----
    {
        float4 q0 = *(const float4*)(s_part + (0 * R + wq) * H + jw0);
        float4 q1 = *(const float4*)(s_part + (1 * R + wq) * H + jw0);
        float4 q2 = *(const float4*)(s_part + (2 * R + wq) * H + jw0);
        float4 q3 = *(const float4*)(s_part + (3 * R + wq) * H + jw0);
        float4 db = *(const float4*)(defB1 + jw0);
        float4 dw = *(const float4*)(defW2 + jw0);
        float pd0 = db.x + (((q0.x + q1.x) + q2.x) + q3.x);
        float pd1 = db.y + (((q0.y + q1.y) + q2.y) + q3.y);
        float pd2 = db.z + (((q0.z + q1.z) + q2.z) + q3.z);
        float pd3 = db.w + (((q0.w + q1.w) + q2.w) + q3.w);
        float dv = fmaxf(pd0, 0.f) * dw.x
                 + fmaxf(pd1, 0.f) * dw.y
                 + fmaxf(pd2, 0.f) * dw.z
                 + fmaxf(pd3, 0.f) * dw.w;
        // jl lanes cover all 128 j (hw halves are duplicates): reduce 32-lane
#pragma unroll
        for (int off = 1; off < 32; off <<= 1) dv += __shfl_xor(dv, off, 64);
        if (lane == 0) {
            float s = dv + defB2[0];
            out[(size_t)N * E + n] = 1.f / (1.f + expf(-s));
        }
    }

    // ---- stage 6: spec GEMM: relu(enc@Wabc + |enc-full|@Wd + bias) -> logits ----
    {
        float acc[8][4];
#pragma unroll
        for (int m = 0; m < 8; m++)
#pragma unroll
            for (int j = 0; j < 4; j++) acc[m][j] = 0.f;
        const float* __restrict__ Wd = specW1 + 3 * H * H;
        for (int k = 0; k < H; k += 4) {
            float4 wa0, wa1, wa2, wa3;
            if (USE_WABC) {
                wa0 = *(const float4*)(wabc + (k + 0) * H + jw0);
                wa1 = *(const float4*)(wabc + (k + 1) * H + jw0);
                wa2 = *(const float4*)(wabc + (k + 2) * H + jw0);
                wa3 = *(const float4*)(wabc + (k + 3) * H + jw0);
            } else {
#pragma unroll
                for (int t = 0; t < 4; t++) {
                    const float* p = specW1 + (k + t) * H + jw0;
                    float4 x0 = *(const float4*)(p);
                    float4 x1 = *(const float4*)(p + H * H);
                    float4 x2 = *(const float4*)(p + 2 * H * H);
                    float4 s4 = make_float4(x0.x + x1.x + x2.x, x0.y + x1.y + x2.y,
                                            x0.z + x1.z + x2.z, x0.w + x1.w + x2.w);
                    if (t == 0) wa0 = s4; else if (t == 1) wa1 = s4;
                    else if (t == 2) wa2 = s4; else wa3 = s4;
                }
            }
            float4 wd0 = *(const float4*)(Wd + (k + 0) * H + jw0);
            float4 wd1 = *(const float4*)(Wd + (k + 1) * H + jw0);
            float4 wd2 = *(const float4*)(Wd + (k + 2) * H + jw0);
            float4 wd3 = *(const float4*)(Wd + (k + 3) * H + jw0);
            float4 f4 = *(const float4*)(s_full + wq * H + k);   // uniform broadcast
#pragma unroll
            for (int m = 0; m < 8; m++) {
                float4 ev = *(const float4*)(wbuf + (hw * 8 + m) * H + k);
                float ax = fabsf(ev.x - f4.x);
                float ay = fabsf(ev.y - f4.y);
                float az = fabsf(ev.z - f4.z);
                float aw = fabsf(ev.w - f4.w);
#pragma unroll
                for (int j = 0; j < 4; j++) {
                    const float* waj0 = &wa0.x, *waj1 = &wa1.x, *waj2 = &wa2.x, *waj3 = &wa3.x;
                    const float* wdj0 = &wd0.x, *wdj1 = &wd1.x, *wdj2 = &wd2.x, *wdj3 = &wd3.x;
                    float a = acc[m][j];
                    a = fmaf(ev.x, waj0[j], a);
                    a = fmaf(ev.y, waj1[j], a);
                    a = fmaf(ev.z, waj2[j], a);
                    a = fmaf(ev.w, waj3[j], a);
                    a = fmaf(ax, wdj0[j], a);
                    a = fmaf(ay, wdj1[j], a);
                    a = fmaf(az, wdj2[j], a);
                    a = fmaf(aw, wdj3[j], a);
                    acc[m][j] = a;
                }
            }
        }
        // epilogue: logit per row via 32-lane reduce; store into own buf slice
        float4 w2 = *(const float4*)(specW2 + jw0);
        __builtin_amdgcn_wave_barrier();   // all encoded reads precede logit writes
#pragma unroll
        for (int m = 0; m < 8; m++) {
            float p = 0.f;
            p += fmaxf(acc[m][0] + biasr.x, 0.f) * w2.x;
            p += fmaxf(acc[m][1] + biasr.y, 0.f) * w2.y;
            p += fmaxf(acc[m][2] + biasr.z, 0.f) * w2.z;
            p += fmaxf(acc[m][3] + biasr.w, 0.f) * w2.w;
#pragma unroll
            for (int off = 1; off < 32; off <<= 1) p += __shfl_xor(p, off, 64);
            if (jl == 0) wbuf[hw * 8 + m] = p;   // logit for expert e = hw*8+m
        }
    }
    __builtin_amdgcn_wave_barrier();

    // ---- stage 7: finalize this wave's n-row (lane 0): top-k + softmax ----
    if (lane == 0) {
        int k = tkPtr[0];
        if (k < 1) k = 1;
        if (k > E - 1) k = E - 1;
        unsigned chosen = 0u;
        for (int kk = 0; kk < k; kk++) {
            float bv = -INFINITY;
            int bi = 0;
            for (int e = 0; e < E; e++) {
                if (e == fi || ((chosen >> e) & 1u)) continue;
                float v = wbuf[e];
                if (v > bv) { bv = v; bi = e; }
            }
            chosen |= (1u << bi);
        }
        float mx = -INFINITY;
        for (int e = 0; e < E; e++)
            if ((chosen >> e) & 1u) { float v = wbuf[e]; if (v > mx) mx = v; }
        float ssum = 0.f;
        for (int e = 0; e < E; e++)
            if ((chosen >> e) & 1u) ssum += expf(wbuf[e] - mx);
        float inv = 1.f / ssum;
        for (int e = 0; e < E; e++) {
            float wv = 0.f;
            if ((chosen >> e) & 1u) wv = expf(wbuf[e] - mx) * inv;
            out[(size_t)n * E + e] = wv;
        }
    }
}

extern "C" void kernel_launch(void* const* d_in, const int* in_sizes, int n_in,
                              void* d_out, int out_size, void* d_ws, size_t ws_size,
                              hipStream_t stream) {
    (void)n_in; (void)out_size;
    const float* tokens = (const float*)d_in[0];
    const float* encW1  = (const float*)d_in[1];
    const float* encB1  = (const float*)d_in[2];
    const float* encW2  = (const float*)d_in[3];
    const float* encB2  = (const float*)d_in[4];
    const float* specW1 = (const float*)d_in[5];
    const float* specB1 = (const float*)d_in[6];
    const float* specW2 = (const float*)d_in[7];
    // d_in[8] = spec_b2 (unused: softmax is shift-invariant)
    const float* defW1  = (const float*)d_in[9];
    const float* defB1  = (const float*)d_in[10];
    const float* defW2  = (const float*)d_in[11];
    const float* defB2  = (const float*)d_in[12];
    const int*   fiPtr  = (const int*)d_in[13];
    const int*   tkPtr  = (const int*)d_in[14];
    float* out = (float*)d_out;

    const int N = in_sizes[0] / (E * D);
    const int grid = (N + R - 1) / R;
    const bool useWs = (d_ws != nullptr) && (ws_size >= (size_t)(H * H * sizeof(float)));

    if (useWs) {
        wabc_prep<<<(H * H + 255) / 256, 256, 0, stream>>>(specW1, (float*)d_ws);
        router_kernel<true><<<grid, 256, 0, stream>>>(
            tokens, encW1, encB1, encW2, encB2, specW1, specB1, specW2,
            defW1, defB1, defW2, defB2, fiPtr, tkPtr, (const float*)d_ws, out, N);
    } else {
        router_kernel<false><<<grid, 256, 0, stream>>>(
            tokens, encW1, encB1, encW2, encB2, specW1, specB1, specW2,
            defW1, defB1, defW2, defB2, fiPtr, tkPtr, nullptr, out, N);
    }
}

// Round 5
// 661.660 us; speedup vs baseline: 1.0901x; 1.0560x over previous
//
#include <hip/hip_runtime.h>
#include <math.h>

#define E 16
#define D 64
#define H 128
#define R 4            // n-rows per block == waves per block

// ---------------------------------------------------------------------------
// Prep: Wabc[c][j] = Wa + Wb + Wc  (spec_W1 rows 0..127, 128..255, 256..383)
// ---------------------------------------------------------------------------
__global__ void wabc_prep(const float* __restrict__ specW1, float* __restrict__ wabc) {
    int i = blockIdx.x * blockDim.x + threadIdx.x;
    if (i < H * H) {
        wabc[i] = specW1[i] + specW1[H * H + i] + specW1[2 * H * H + i];
    }
}

// ---------------------------------------------------------------------------
// Fused router. Block = 256 threads (4 waves). Wave wq owns n-row
// (blockIdx.x*R + wq) and a private 8 KB LDS slice. Stage 5 (bias/defer GEMV)
// is block-cooperative with a 4-way c-split (per-wave weight traffic 320->80KB).
//
// OCCUPANCY MODEL (r0-r4 evidence): effective per-EU VGPR pool ~256 for
// wave64: <=64 VGPR -> 4 waves/EU, <=85 -> 3, <=128 -> 2. r3/r4 at 92-108
// VGPR ran 2/EU (22%) despite LDS allowing more. Fix: __launch_bounds__(256,3)
// (hipcc VGPR budget ~85) + structural register-pressure cuts:
//   - stage 6 split into two K-passes (Wabc pass, then Wd pass): peak ~92->~70
//   - GEMV split into B-loop then D-loop (accB dead before D stream)
//   - bias kept in LDS (dead s_mabs row) instead of registers across stage 6
// LDS = 47,104 B -> 3 blocks/CU = 12 waves/CU, matching the 3/EU target.
// ---------------------------------------------------------------------------
template <bool USE_WABC>
__global__ __launch_bounds__(256, 3)
void router_kernel(const float* __restrict__ tokens,
                   const float* __restrict__ encW1, const float* __restrict__ encB1,
                   const float* __restrict__ encW2, const float* __restrict__ encB2,
                   const float* __restrict__ specW1, const float* __restrict__ specB1,
                   const float* __restrict__ specW2,
                   const float* __restrict__ defW1, const float* __restrict__ defB1,
                   const float* __restrict__ defW2, const float* __restrict__ defB2,
                   const int* __restrict__ fiPtr, const int* __restrict__ tkPtr,
                   const float* __restrict__ wabc,
                   float* __restrict__ out, int N) {
    __shared__ float buf[R * E * H];     // 32 KB, wave-partitioned
    __shared__ float s_full[R * H];      // 2 KB
    __shared__ float s_glob[R * H];      // 2 KB
    __shared__ float s_mabs[R * H];      // 2 KB; after GEMV: bias per row
    __shared__ float s_part[R * R * H];  // 8 KB: GEMV partials [wave][row][H]

    const int tid  = threadIdx.x;
    const int lane = tid & 63;
    const int wq   = tid >> 6;
    const int n    = blockIdx.x * R + wq;
    const bool active = (n < N);       // wave-uniform; all waves reach barriers

    const int fi  = fiPtr[0];
    const int hw  = lane >> 5;         // half-wave: rows 0..7 / 8..15 (or K-half)
    const int jl  = lane & 31;
    const int jw0 = jl * 4;            // this lane's 4-col chunk
    float* __restrict__ wbuf = buf + wq * (E * H);

    if (active) {
        // ---- stage 1: coalesced token load: 16 expert-rows x 64 = 4 KB ----
        {
            const float4* __restrict__ src = (const float4*)(tokens + (size_t)n * (E * D));
            float4* dst = (float4*)wbuf;
#pragma unroll
            for (int it = 0; it < 4; it++) dst[lane + it * 64] = src[lane + it * 64];
        }
        __builtin_amdgcn_wave_barrier();

        // ---- stage 2: enc1  h = relu(tok @ W1 + b1), K=64; in place ----
        {
            float acc[8][4];
#pragma unroll
            for (int m = 0; m < 8; m++)
#pragma unroll
                for (int j = 0; j < 4; j++) acc[m][j] = 0.f;
#pragma unroll 2
            for (int k = 0; k < D; k += 4) {
                float4 w0 = *(const float4*)(encW1 + (k + 0) * H + jw0);
                float4 w1 = *(const float4*)(encW1 + (k + 1) * H + jw0);
                float4 w2 = *(const float4*)(encW1 + (k + 2) * H + jw0);
                float4 w3 = *(const float4*)(encW1 + (k + 3) * H + jw0);
#pragma unroll
                for (int m = 0; m < 8; m++) {
                    float4 t = *(const float4*)(wbuf + (hw * 8 + m) * D + k);
                    acc[m][0] = fmaf(t.w, w3.x, fmaf(t.z, w2.x, fmaf(t.y, w1.x, fmaf(t.x, w0.x, acc[m][0]))));
                    acc[m][1] = fmaf(t.w, w3.y, fmaf(t.z, w2.y, fmaf(t.y, w1.y, fmaf(t.x, w0.y, acc[m][1]))));
                    acc[m][2] = fmaf(t.w, w3.z, fmaf(t.z, w2.z, fmaf(t.y, w1.z, fmaf(t.x, w0.z, acc[m][2]))));
                    acc[m][3] = fmaf(t.w, w3.w, fmaf(t.z, w2.w, fmaf(t.y, w1.w, fmaf(t.x, w0.w, acc[m][3]))));
                }
            }
            float4 b = *(const float4*)(encB1 + jw0);
            __builtin_amdgcn_wave_barrier();   // all token reads precede h writes
#pragma unroll
            for (int m = 0; m < 8; m++) {
                float4 o;
                o.x = fmaxf(acc[m][0] + b.x, 0.f);
                o.y = fmaxf(acc[m][1] + b.y, 0.f);
                o.z = fmaxf(acc[m][2] + b.z, 0.f);
                o.w = fmaxf(acc[m][3] + b.w, 0.f);
                *(float4*)(wbuf + (hw * 8 + m) * H + jw0) = o;
            }
        }
        __builtin_amdgcn_wave_barrier();

        // ---- stage 3: enc2  encoded = relu(h @ W2 + b2), K=128; in place ----
        {
            float acc[8][4];
#pragma unroll
            for (int m = 0; m < 8; m++)
#pragma unroll
                for (int j = 0; j < 4; j++) acc[m][j] = 0.f;
#pragma unroll 2
            for (int k = 0; k < H; k += 4) {
                float4 w0 = *(const float4*)(encW2 + (k + 0) * H + jw0);
                float4 w1 = *(const float4*)(encW2 + (k + 1) * H + jw0);
                float4 w2 = *(const float4*)(encW2 + (k + 2) * H + jw0);
                float4 w3 = *(const float4*)(encW2 + (k + 3) * H + jw0);
#pragma unroll
                for (int m = 0; m < 8; m++) {
                    float4 t = *(const float4*)(wbuf + (hw * 8 + m) * H + k);
                    acc[m][0] = fmaf(t.w, w3.x, fmaf(t.z, w2.x, fmaf(t.y, w1.x, fmaf(t.x, w0.x, acc[m][0]))));
                    acc[m][1] = fmaf(t.w, w3.y, fmaf(t.z, w2.y, fmaf(t.y, w1.y, fmaf(t.x, w0.y, acc[m][1]))));
                    acc[m][2] = fmaf(t.w, w3.z, fmaf(t.z, w2.z, fmaf(t.y, w1.z, fmaf(t.x, w0.z, acc[m][2]))));
                    acc[m][3] = fmaf(t.w, w3.w, fmaf(t.z, w2.w, fmaf(t.y, w1.w, fmaf(t.x, w0.w, acc[m][3]))));
                }
            }
            float4 b = *(const float4*)(encB2 + jw0);
            __builtin_amdgcn_wave_barrier();   // all h reads precede encoded writes
#pragma unroll
            for (int m = 0; m < 8; m++) {
                float4 o;
                o.x = fmaxf(acc[m][0] + b.x, 0.f);
                o.y = fmaxf(acc[m][1] + b.y, 0.f);
                o.z = fmaxf(acc[m][2] + b.z, 0.f);
                o.w = fmaxf(acc[m][3] + b.w, 0.f);
                *(float4*)(wbuf + (hw * 8 + m) * H + jw0) = o;
            }
        }
        __builtin_amdgcn_wave_barrier();

        // ---- stage 4: stats (full, glob mean, mean|delta|), 2 cols/lane ----
        {
            const int c2 = lane * 2;
            float2 fc = *(const float2*)(wbuf + fi * H + c2);
            float sx = 0.f, sy = 0.f, mx = 0.f, my = 0.f;
#pragma unroll
            for (int e = 0; e < E; e++) {
                float2 v = *(const float2*)(wbuf + e * H + c2);
                sx += v.x; sy += v.y;
                mx += fabsf(v.x - fc.x); my += fabsf(v.y - fc.y);
            }
            *(float2*)(s_full + wq * H + c2) = fc;
            *(float2*)(s_glob + wq * H + c2) = make_float2(sx * 0.0625f, sy * 0.0625f);
            *(float2*)(s_mabs + wq * H + c2) = make_float2(mx * 0.0625f, my * 0.0625f);
        }
    }
    __syncthreads();   // #1: all rows' stats visible to all waves

    // ---- stage 5a-B: bias-GEMV partials (Wb, Wc), c-split across waves.
    //      Wave wq covers c in [wq*32, wq*32+32) for ALL R rows. ----
    {
        const float* __restrict__ Wb = specW1 + H * H;
        const float* __restrict__ Wc = specW1 + 2 * H * H;
        const int cbase = wq * 32 + hw * 16;
        float accB[R][4];
#pragma unroll
        for (int r = 0; r < R; r++)
#pragma unroll
            for (int j = 0; j < 4; j++) accB[r][j] = 0.f;
        for (int c4 = 0; c4 < 4; c4++) {           // 4 chunks of 4 c
            float4 fv4[R], gv4[R];
#pragma unroll
            for (int r = 0; r < R; r++) {
                fv4[r] = *(const float4*)(s_full + r * H + cbase + c4 * 4);
                gv4[r] = *(const float4*)(s_glob + r * H + cbase + c4 * 4);
            }
#pragma unroll
            for (int cc = 0; cc < 4; cc++) {
                const int c = cbase + c4 * 4 + cc;
                float4 wb = *(const float4*)(Wb + c * H + jw0);
                float4 wc = *(const float4*)(Wc + c * H + jw0);
#pragma unroll
                for (int r = 0; r < R; r++) {
                    const float fv = (&fv4[r].x)[cc];
                    const float gv = (&gv4[r].x)[cc];
                    accB[r][0] = fmaf(gv, wc.x, fmaf(fv, wb.x, accB[r][0]));
                    accB[r][1] = fmaf(gv, wc.y, fmaf(fv, wb.y, accB[r][1]));
                    accB[r][2] = fmaf(gv, wc.z, fmaf(fv, wb.z, accB[r][2]));
                    accB[r][3] = fmaf(gv, wc.w, fmaf(fv, wb.w, accB[r][3]));
                }
            }
        }
#pragma unroll
        for (int r = 0; r < R; r++)
#pragma unroll
            for (int j = 0; j < 4; j++)
                accB[r][j] += __shfl_xor(accB[r][j], 32, 64);
        // store B-partials (hw splits rows: no duplicate writes)
#pragma unroll
        for (int rr = 0; rr < 2; rr++) {
            const int r = hw * 2 + rr;
            *(float4*)(s_part + (wq * R + r) * H + jw0) =
                make_float4(accB[r][0], accB[r][1], accB[r][2], accB[r][3]);
        }
    }

    // ---- stage 5a-D: defer-GEMV partials (defW1 rows 0/1/2), same c-split ----
    float accD[R][4];
    {
        const int cbase = wq * 32 + hw * 16;
#pragma unroll
        for (int r = 0; r < R; r++)
#pragma unroll
            for (int j = 0; j < 4; j++) accD[r][j] = 0.f;
        for (int c4 = 0; c4 < 4; c4++) {
            float4 fv4[R], gv4[R], mv4[R];
#pragma unroll
            for (int r = 0; r < R; r++) {
                fv4[r] = *(const float4*)(s_full + r * H + cbase + c4 * 4);
                gv4[r] = *(const float4*)(s_glob + r * H + cbase + c4 * 4);
                mv4[r] = *(const float4*)(s_mabs + r * H + cbase + c4 * 4);
            }
#pragma unroll
            for (int cc = 0; cc < 4; cc++) {
                const int c = cbase + c4 * 4 + cc;
                float4 d0 = *(const float4*)(defW1 + c * H + jw0);
                float4 d1 = *(const float4*)(defW1 + (H + c) * H + jw0);
                float4 d2 = *(const float4*)(defW1 + (2 * H + c) * H + jw0);
#pragma unroll
                for (int r = 0; r < R; r++) {
                    const float fv = (&fv4[r].x)[cc];
                    const float gv = (&gv4[r].x)[cc];
                    const float mv = (&mv4[r].x)[cc];
                    accD[r][0] = fmaf(mv, d2.x, fmaf(gv, d1.x, fmaf(fv, d0.x, accD[r][0])));
                    accD[r][1] = fmaf(mv, d2.y, fmaf(gv, d1.y, fmaf(fv, d0.y, accD[r][1])));
                    accD[r][2] = fmaf(mv, d2.z, fmaf(gv, d1.z, fmaf(fv, d0.z, accD[r][2])));
                    accD[r][3] = fmaf(mv, d2.w, fmaf(gv, d1.w, fmaf(fv, d0.w, accD[r][3])));
                }
            }
        }
#pragma unroll
        for (int r = 0; r < R; r++)
#pragma unroll
            for (int j = 0; j < 4; j++)
                accD[r][j] += __shfl_xor(accD[r][j], 32, 64);
    }
    __syncthreads();   // #2: B-partials visible; all stats reads (incl s_mabs) done

    // ---- stage 5b: combine B-partials -> bias, stored in dead s_mabs row wq.
    //      Wave-private (wave wq writes+reads only row wq). hw halves write
    //      identical values to the same address (benign). ----
    float* __restrict__ s_bias = s_mabs;
    {
        float4 p0 = *(const float4*)(s_part + (0 * R + wq) * H + jw0);
        float4 p1 = *(const float4*)(s_part + (1 * R + wq) * H + jw0);
        float4 p2 = *(const float4*)(s_part + (2 * R + wq) * H + jw0);
        float4 p3 = *(const float4*)(s_part + (3 * R + wq) * H + jw0);
        float4 sb = *(const float4*)(specB1 + jw0);
        float4 bn;
        bn.x = sb.x - (((p0.x + p1.x) + p2.x) + p3.x);
        bn.y = sb.y - (((p0.y + p1.y) + p2.y) + p3.y);
        bn.z = sb.z - (((p0.z + p1.z) + p2.z) + p3.z);
        bn.w = sb.w - (((p0.w + p1.w) + p2.w) + p3.w);
        *(float4*)(s_bias + wq * H + jw0) = bn;
    }
    __syncthreads();   // #3: all B-partial reads done before slab reuse

    // ---- stage 5c: store D-partials into reused slab ----
    {
#pragma unroll
        for (int rr = 0; rr < 2; rr++) {
            const int r = hw * 2 + rr;
            *(float4*)(s_part + (wq * R + r) * H + jw0) =
                make_float4(accD[r][0], accD[r][1], accD[r][2], accD[r][3]);
        }
    }
    __syncthreads();   // #4: D-partials ready

    if (!active) return;

    // ---- stage 5d: defer head: combine D-partials, relu, dot w/ defW2 ----
    {
        float4 q0 = *(const float4*)(s_part + (0 * R + wq) * H + jw0);
        float4 q1 = *(const float4*)(s_part + (1 * R + wq) * H + jw0);
        float4 q2 = *(const float4*)(s_part + (2 * R + wq) * H + jw0);
        float4 q3 = *(const float4*)(s_part + (3 * R + wq) * H + jw0);
        float4 db = *(const float4*)(defB1 + jw0);
        float4 dw = *(const float4*)(defW2 + jw0);
        float pd0 = db.x + (((q0.x + q1.x) + q2.x) + q3.x);
        float pd1 = db.y + (((q0.y + q1.y) + q2.y) + q3.y);
        float pd2 = db.z + (((q0.z + q1.z) + q2.z) + q3.z);
        float pd3 = db.w + (((q0.w + q1.w) + q2.w) + q3.w);
        float dv = fmaxf(pd0, 0.f) * dw.x
                 + fmaxf(pd1, 0.f) * dw.y
                 + fmaxf(pd2, 0.f) * dw.z
                 + fmaxf(pd3, 0.f) * dw.w;
        // jl lanes cover all 128 j (hw halves are duplicates): reduce 32-lane
#pragma unroll
        for (int off = 1; off < 32; off <<= 1) dv += __shfl_xor(dv, off, 64);
        if (lane == 0) {
            float s = dv + defB2[0];
            out[(size_t)N * E + n] = 1.f / (1.f + expf(-s));
        }
    }

    // ---- stage 6: spec GEMM in two K-passes (register-pressure split):
    //      pass A: acc += enc @ Wabc;  pass B: acc += |enc-full| @ Wd ----
    {
        float acc[8][4];
#pragma unroll
        for (int m = 0; m < 8; m++)
#pragma unroll
            for (int j = 0; j < 4; j++) acc[m][j] = 0.f;

        // pass A: enc @ Wabc
        for (int k = 0; k < H; k += 4) {
            float4 wa0, wa1, wa2, wa3;
            if (USE_WABC) {
                wa0 = *(const float4*)(wabc + (k + 0) * H + jw0);
                wa1 = *(const float4*)(wabc + (k + 1) * H + jw0);
                wa2 = *(const float4*)(wabc + (k + 2) * H + jw0);
                wa3 = *(const float4*)(wabc + (k + 3) * H + jw0);
            } else {
#pragma unroll
                for (int t = 0; t < 4; t++) {
                    const float* p = specW1 + (k + t) * H + jw0;
                    float4 x0 = *(const float4*)(p);
                    float4 x1 = *(const float4*)(p + H * H);
                    float4 x2 = *(const float4*)(p + 2 * H * H);
                    float4 s4 = make_float4(x0.x + x1.x + x2.x, x0.y + x1.y + x2.y,
                                            x0.z + x1.z + x2.z, x0.w + x1.w + x2.w);
                    if (t == 0) wa0 = s4; else if (t == 1) wa1 = s4;
                    else if (t == 2) wa2 = s4; else wa3 = s4;
                }
            }
#pragma unroll
            for (int m = 0; m < 8; m++) {
                float4 ev = *(const float4*)(wbuf + (hw * 8 + m) * H + k);
#pragma unroll
                for (int j = 0; j < 4; j++) {
                    const float* waj0 = &wa0.x, *waj1 = &wa1.x, *waj2 = &wa2.x, *waj3 = &wa3.x;
                    float a = acc[m][j];
                    a = fmaf(ev.x, waj0[j], a);
                    a = fmaf(ev.y, waj1[j], a);
                    a = fmaf(ev.z, waj2[j], a);
                    a = fmaf(ev.w, waj3[j], a);
                    acc[m][j] = a;
                }
            }
        }

        // pass B: |enc - full| @ Wd
        const float* __restrict__ Wd = specW1 + 3 * H * H;
        for (int k = 0; k < H; k += 4) {
            float4 wd0 = *(const float4*)(Wd + (k + 0) * H + jw0);
            float4 wd1 = *(const float4*)(Wd + (k + 1) * H + jw0);
            float4 wd2 = *(const float4*)(Wd + (k + 2) * H + jw0);
            float4 wd3 = *(const float4*)(Wd + (k + 3) * H + jw0);
            float4 f4 = *(const float4*)(s_full + wq * H + k);   // uniform broadcast
#pragma unroll
            for (int m = 0; m < 8; m++) {
                float4 ev = *(const float4*)(wbuf + (hw * 8 + m) * H + k);
                float ax = fabsf(ev.x - f4.x);
                float ay = fabsf(ev.y - f4.y);
                float az = fabsf(ev.z - f4.z);
                float aw = fabsf(ev.w - f4.w);
#pragma unroll
                for (int j = 0; j < 4; j++) {
                    const float* wdj0 = &wd0.x, *wdj1 = &wd1.x, *wdj2 = &wd2.x, *wdj3 = &wd3.x;
                    float a = acc[m][j];
                    a = fmaf(ax, wdj0[j], a);
                    a = fmaf(ay, wdj1[j], a);
                    a = fmaf(az, wdj2[j], a);
                    a = fmaf(aw, wdj3[j], a);
                    acc[m][j] = a;
                }
            }
        }

        // epilogue: logit per row via 32-lane reduce; store into own buf slice
        float4 bn = *(const float4*)(s_bias + wq * H + jw0);
        float4 w2 = *(const float4*)(specW2 + jw0);
        __builtin_amdgcn_wave_barrier();   // all encoded reads precede logit writes
#pragma unroll
        for (int m = 0; m < 8; m++) {
            float p = 0.f;
            p += fmaxf(acc[m][0] + bn.x, 0.f) * w2.x;
            p += fmaxf(acc[m][1] + bn.y, 0.f) * w2.y;
            p += fmaxf(acc[m][2] + bn.z, 0.f) * w2.z;
            p += fmaxf(acc[m][3] + bn.w, 0.f) * w2.w;
#pragma unroll
            for (int off = 1; off < 32; off <<= 1) p += __shfl_xor(p, off, 64);
            if (jl == 0) wbuf[hw * 8 + m] = p;   // logit for expert e = hw*8+m
        }
    }
    __builtin_amdgcn_wave_barrier();

    // ---- stage 7: finalize this wave's n-row (lane 0): top-k + softmax ----
    if (lane == 0) {
        int k = tkPtr[0];
        if (k < 1) k = 1;
        if (k > E - 1) k = E - 1;
        unsigned chosen = 0u;
        for (int kk = 0; kk < k; kk++) {
            float bv = -INFINITY;
            int bi = 0;
            for (int e = 0; e < E; e++) {
                if (e == fi || ((chosen >> e) & 1u)) continue;
                float v = wbuf[e];
                if (v > bv) { bv = v; bi = e; }
            }
            chosen |= (1u << bi);
        }
        float mx = -INFINITY;
        for (int e = 0; e < E; e++)
            if ((chosen >> e) & 1u) { float v = wbuf[e]; if (v > mx) mx = v; }
        float ssum = 0.f;
        for (int e = 0; e < E; e++)
            if ((chosen >> e) & 1u) ssum += expf(wbuf[e] - mx);
        float inv = 1.f / ssum;
        for (int e = 0; e < E; e++) {
            float wv = 0.f;
            if ((chosen >> e) & 1u) wv = expf(wbuf[e] - mx) * inv;
            out[(size_t)n * E + e] = wv;
        }
    }
}

extern "C" void kernel_launch(void* const* d_in, const int* in_sizes, int n_in,
                              void* d_out, int out_size, void* d_ws, size_t ws_size,
                              hipStream_t stream) {
    (void)n_in; (void)out_size;
    const float* tokens = (const float*)d_in[0];
    const float* encW1  = (const float*)d_in[1];
    const float* encB1  = (const float*)d_in[2];
    const float* encW2  = (const float*)d_in[3];
    const float* encB2  = (const float*)d_in[4];
    const float* specW1 = (const float*)d_in[5];
    const float* specB1 = (const float*)d_in[6];
    const float* specW2 = (const float*)d_in[7];
    // d_in[8] = spec_b2 (unused: softmax is shift-invariant)
    const float* defW1  = (const float*)d_in[9];
    const float* defB1  = (const float*)d_in[10];
    const float* defW2  = (const float*)d_in[11];
    const float* defB2  = (const float*)d_in[12];
    const int*   fiPtr  = (const int*)d_in[13];
    const int*   tkPtr  = (const int*)d_in[14];
    float* out = (float*)d_out;

    const int N = in_sizes[0] / (E * D);
    const int grid = (N + R - 1) / R;
    const bool useWs = (d_ws != nullptr) && (ws_size >= (size_t)(H * H * sizeof(float)));

    if (useWs) {
        wabc_prep<<<(H * H + 255) / 256, 256, 0, stream>>>(specW1, (float*)d_ws);
        router_kernel<true><<<grid, 256, 0, stream>>>(
            tokens, encW1, encB1, encW2, encB2, specW1, specB1, specW2,
            defW1, defB1, defW2, defB2, fiPtr, tkPtr, (const float*)d_ws, out, N);
    } else {
        router_kernel<false><<<grid, 256, 0, stream>>>(
            tokens, encW1, encB1, encW2, encB2, specW1, specB1, specW2,
            defW1, defB1, defW2, defB2, fiPtr, tkPtr, nullptr, out, N);
    }
}